// Round 11
// baseline (214.657 us; speedup 1.0000x reference)
//
#include <hip/hip_runtime.h>
#include <hip/hip_bf16.h>
#include <stdint.h>

typedef __hip_bfloat16 bf16;
typedef __attribute__((ext_vector_type(8))) short short8;
typedef __attribute__((ext_vector_type(16))) float f32x16;

#define DEVI __device__ __forceinline__

static constexpr long IMAG_OFF = 8192l * 512;   // offset of imag plane in d_out

DEVI unsigned short f2b(float f) {
  bf16 h = __float2bfloat16(f);
  unsigned short u;
  __builtin_memcpy(&u, &h, 2);
  return u;
}

DEVI float b2f(unsigned short u) {
  unsigned int x = (unsigned int)u << 16;
  float f;
  __builtin_memcpy(&f, &x, 4);
  return f;
}

#define GLD16(g, l) __builtin_amdgcn_global_load_lds( \
    (const __attribute__((address_space(1))) void*)(g), \
    (__attribute__((address_space(3))) void*)(l), 16, 0, 0)

// ---------------------------------------------------------------------------
// Pack x_real/x_imag (fp32) -> xpack bf16 (8192, 1024) = [real | imag]
// ---------------------------------------------------------------------------
__global__ __launch_bounds__(256) void pack_x_kernel(
    const float* __restrict__ xr, const float* __restrict__ xi,
    unsigned short* __restrict__ xp) {
  const int t = blockIdx.x * 256 + threadIdx.x;
  const int m = t >> 8;
  const int d = (t & 255) * 4;
  const float* src = (d < 512) ? (xr + (long)m * 512 + d)
                               : (xi + (long)m * 512 + (d - 512));
  float4 v = *reinterpret_cast<const float4*>(src);
  ushort4 o;
  o.x = f2b(v.x); o.y = f2b(v.y); o.z = f2b(v.z); o.w = f2b(v.w);
  *reinterpret_cast<ushort4*>(xp + (long)m * 1024 + d) = o;
}

// ---------------------------------------------------------------------------
// Build Wbig (1024x1024 bf16) per layer: [[Wr, -Wi], [Wi, Wr]] and packed bias
// ---------------------------------------------------------------------------
struct WArgs {
  const float* wr[5]; const float* wi[5];
  const float* br[5]; const float* bi[5];
};

__global__ __launch_bounds__(256) void pack_w_kernel(
    WArgs a, unsigned short* __restrict__ W, float* __restrict__ bias) {
  const int L = blockIdx.z;
  const int t = blockIdx.x * 256 + threadIdx.x;
  const int n = t >> 8;
  const int k = (t & 255) * 4;
  const float* wr = a.wr[L]; const float* wi = a.wi[L];
  const float* src; float sgn = 1.0f;
  if (n < 512) {
    if (k < 512) src = wr + (long)n * 512 + k;
    else { src = wi + (long)n * 512 + (k - 512); sgn = -1.0f; }
  } else {
    if (k < 512) src = wi + (long)(n - 512) * 512 + k;
    else         src = wr + (long)(n - 512) * 512 + (k - 512);
  }
  float4 v = *reinterpret_cast<const float4*>(src);
  ushort4 o;
  o.x = f2b(sgn * v.x); o.y = f2b(sgn * v.y);
  o.z = f2b(sgn * v.z); o.w = f2b(sgn * v.w);
  *reinterpret_cast<ushort4*>(W + (long)L * 1024 * 1024 + (long)n * 1024 + k) = o;
  if (t < 1024)
    bias[L * 1024 + t] = (t < 512) ? a.br[L][t] : a.bi[L][t - 512];
}

// ---------------------------------------------------------------------------
// gemm3 (r8 schedule, r11 inner shape): C[m,n] = sum_k A[m,k]*B[n,k]
// Tile 128(M) x 256(N), BK=32, 512 threads = 8 waves (2M x 4N), wave 64x64.
// THREE LDS buffers (72 KiB -> 2 blocks/CU), distance-2 prefetch ring,
// counted vmcnt(3), ONE barrier per K-tile, setprio.
// r11: MFMA shape 32x32x16 (8 instr/K-tile @32k FLOP vs 16 @16k -- matrix-
// pipe time -17% per measured ceilings 2382 vs 2075 TF; same 8 ds_read_b128
// per K-tile). Swizzle selector extended with row bit4:
//   sel(row) = ((row>>1)&3) ^ ((row>>4)&1)
// applied BOTH at staging source and fragment read (rule #21) -- keeps
// uniform 8 lanes per 16B bank-group for the 32-row fragment reads.
// C/D map (operand-swapped, m74/m101): m = lane&31,
//   n = (reg&3) + 8*(reg>>2) + 4*(lane>>5) -> float4 quads of consecutive n.
// GM: 0 = plain 2D/3D grid; 2 = batched 1D (z = id&7 pins batch -> XCD).
// OM: 0 = bf16 C; 2 = fp32 split re/im into d_out;
//     3 = |complex|/sqrt(512) interleaved re/im cols -> BF16 (ldc=1024);
//     4 = fused QKV epilogue (q plain, k -> interleaved kmod, v -> vt direct)
// ---------------------------------------------------------------------------
template<int OM, bool BIAS, bool ACT, int GM>
__global__ __launch_bounds__(512) void gemm3_kernel(
    const bf16* __restrict__ A, const bf16* __restrict__ Bm,
    void* __restrict__ C0, void* __restrict__ C1, void* __restrict__ C2,
    const float* __restrict__ bias, int N, int K,
    long sA, long sB, long sC) {
  __shared__ __align__(16) bf16 sm[3 * 12288];   // buf: A 128x32 (8KB) + B 256x32 (16KB)
  const int tid  = threadIdx.x;
  const int lane = tid & 63, wave = tid >> 6;
  const int rl = lane & 31, hi = lane >> 5;
  const int wr = wave >> 2, wc = wave & 3;

  int bm, bn, z;
  if (GM == 2) {
    const int id = blockIdx.x;
    z = id & 7;                 // batch -> XCD (dispatch is round-robin id%8)
    const int local = id >> 3;
    bm = local & 7;
    bn = local >> 3;
  } else {
    bm = blockIdx.x; bn = blockIdx.y; z = blockIdx.z;
  }
  const int m0 = bm * 128, n0 = bn * 256;

  const bf16* Ab = A  + (long)z * sA;
  const bf16* Bb = Bm + (long)z * sB;
  // staging: linear LDS dest (gload_lds requirement); source chunk
  // pre-swizzled with sel(row), row = tid>>2:
  //   sel = ((tid>>3)&3) ^ ((tid>>6)&1)
  const int srow = tid >> 2;
  const int schk = ((tid & 3) ^ ((tid >> 3) & 3) ^ ((tid >> 6) & 1)) * 8;
  const bf16* gA  = Ab + (long)(m0 + srow) * K + schk;
  const bf16* gB0 = Bb + (long)(n0 + srow) * K + schk;
  const bf16* gB1 = gB0 + (long)128 * K;   // rows +128: sel unchanged (bit4 of 128>>4=8 -> &1=0)
  char* const lb = (char*)sm + tid * 16;

#define STG3(buf, kt) do { \
    GLD16(gA  + (kt), lb + (buf) * 24576); \
    GLD16(gB0 + (kt), lb + (buf) * 24576 + 8192); \
    GLD16(gB1 + (kt), lb + (buf) * 24576 + 16384); } while (0)

  f32x16 acc[2][2] = {};
  // fragment read: row = (frag base) + rl; global k-chunk c = hi + 2*ks;
  // LDS chunk = c ^ sel(rl)  (frag bases are multiples of 32 -> sel(rl) only)
  const int selr = ((rl >> 1) & 3) ^ ((rl >> 4) & 1);
  int chk[2];
  chk[0] = ((hi) ^ selr) * 8;
  chk[1] = ((hi + 2) ^ selr) * 8;
  const int arow = (wr * 64 + rl) * 32;          // + mf*1024 (32 rows * 32)
  const int brow = 4096 + (wc * 64 + rl) * 32;   // + nf*1024

  STG3(0, 0);
  STG3(1, 32);
  asm volatile("s_waitcnt vmcnt(3)" ::: "memory");
  __builtin_amdgcn_s_barrier();

  const int nt = K >> 5;
  int bc = 0, bs = 2;
  for (int t = 0; t < nt; ++t) {
    if (t + 2 < nt) STG3(bs, (t + 2) << 5);   // burst-issue distance-2 prefetch
    const bf16* S = sm + bc * 12288;
    short8 af[2][2], bq[2][2];
#pragma unroll
    for (int mf = 0; mf < 2; ++mf)
#pragma unroll
      for (int ks = 0; ks < 2; ++ks)
        af[mf][ks] = *reinterpret_cast<const short8*>(S + arow + mf * 1024 + chk[ks]);
#pragma unroll
    for (int nf = 0; nf < 2; ++nf)
#pragma unroll
      for (int ks = 0; ks < 2; ++ks)
        bq[nf][ks] = *reinterpret_cast<const short8*>(S + brow + nf * 1024 + chk[ks]);
    __builtin_amdgcn_s_setprio(1);
#pragma unroll
    for (int ks = 0; ks < 2; ++ks)
#pragma unroll
      for (int mf = 0; mf < 2; ++mf)
#pragma unroll
        for (int nf = 0; nf < 2; ++nf)
          acc[mf][nf] = __builtin_amdgcn_mfma_f32_32x32x16_bf16(
              bq[nf][ks], af[mf][ks], acc[mf][nf], 0, 0, 0);
    __builtin_amdgcn_s_setprio(0);
    // counted gate: tile t+1 guaranteed in LDS for ALL waves only after the
    // barrier below (vmcnt is per-wave).
    if (t < nt - 2) asm volatile("s_waitcnt vmcnt(3)" ::: "memory");
    else            asm volatile("s_waitcnt vmcnt(0)" ::: "memory");
    __builtin_amdgcn_s_barrier();
    bc = (bc == 2) ? 0 : bc + 1;
    bs = (bs == 2) ? 0 : bs + 1;
  }
#undef STG3

  // epilogue: D = mfma(B_frag, A_frag):
  //   m = m0 + wr*64 + mf*32 + rl
  //   n = n0 + wc*64 + nf*32 + qd*8 + hi*4 + (reg&3), reg = qd*4 + (reg&3)
  const int mbase = m0 + wr * 64 + rl;
  const int nbase = n0 + wc * 64 + hi * 4;
#pragma unroll
  for (int mf = 0; mf < 2; ++mf) {
    const long rm = mbase + mf * 32;
#pragma unroll
    for (int nf = 0; nf < 2; ++nf) {
#pragma unroll
      for (int qd = 0; qd < 4; ++qd) {
        const int cn = nbase + nf * 32 + qd * 8;
        float4 f;
        f.x = acc[mf][nf][qd * 4 + 0];
        f.y = acc[mf][nf][qd * 4 + 1];
        f.z = acc[mf][nf][qd * 4 + 2];
        f.w = acc[mf][nf][qd * 4 + 3];
        if (BIAS) {
          float4 b4 = *reinterpret_cast<const float4*>(bias + cn);
          f.x += b4.x; f.y += b4.y; f.z += b4.z; f.w += b4.w;
        }
        if (ACT) {
          f.x = (f.x >= 0.f) ? f.x : 0.01f * f.x;
          f.y = (f.y >= 0.f) ? f.y : 0.01f * f.y;
          f.z = (f.z >= 0.f) ? f.z : 0.01f * f.z;
          f.w = (f.w >= 0.f) ? f.w : 0.01f * f.w;
        }
        if (OM == 0) {
          unsigned short* C = (unsigned short*)C0 + (long)z * sC;
          ushort4 o; o.x = f2b(f.x); o.y = f2b(f.y); o.z = f2b(f.z); o.w = f2b(f.w);
          *reinterpret_cast<ushort4*>(C + rm * N + cn) = o;
        } else if (OM == 2) {
          float* O = (float*)C0;
          if (cn < 512) *reinterpret_cast<float4*>(O + rm * 512 + cn) = f;
          else          *reinterpret_cast<float4*>(O + IMAG_OFF + rm * 512 + (cn - 512)) = f;
        } else if (OM == 3) {
          // |s|/sqrt(512) as BF16; interleaved re/im pairs are adjacent regs
          unsigned short* S = (unsigned short*)C0 + (long)z * sC;
          const float scale = 0.044194173824159216f;   // 1/sqrt(512)
          ushort2 o;
          o.x = f2b(sqrtf(f.x * f.x + f.y * f.y) * scale);
          o.y = f2b(sqrtf(f.z * f.z + f.w * f.w) * scale);
          *reinterpret_cast<ushort2*>(S + rm * 1024 + (cn >> 1)) = o;
        } else if (OM == 4) {
          if (cn < 1024) {            // q
            unsigned short* Q = (unsigned short*)C0;
            ushort4 o; o.x = f2b(f.x); o.y = f2b(f.y); o.z = f2b(f.z); o.w = f2b(f.w);
            *reinterpret_cast<ushort4*>(Q + rm * 1024 + cn) = o;
          } else if (cn < 2048) {     // k -> interleaved kmod
            const int d = cn - 1024;
            const int b = (int)(rm >> 10), tt = (int)(rm & 1023);
            unsigned short* KM = (unsigned short*)C1;
            const float s = (d < 512) ? 1.0f : -1.0f;
            ushort4 o1, o2;
            o1.x = f2b(s * f.x); o1.y = f2b(s * f.y);
            o1.z = f2b(s * f.z); o1.w = f2b(s * f.w);
            o2.x = f2b(f.x); o2.y = f2b(f.y); o2.z = f2b(f.z); o2.w = f2b(f.w);
            // row 2t: Re-transform [kr | -ki]; row 2t+1: Im-transform [ki | kr]
            *reinterpret_cast<ushort4*>(KM + ((long)(b << 11) + 2 * tt)     * 1024 + d)         = o1;
            *reinterpret_cast<ushort4*>(KM + ((long)(b << 11) + 2 * tt + 1) * 1024 + (d ^ 512)) = o2;
          } else {                    // v -> vt[b][d][t] directly (fused transpose)
            unsigned short* VT = (unsigned short*)C2;
            const int d = cn - 2048;
            const int b = (int)(rm >> 10), tt = (int)(rm & 1023);
            unsigned short* p = VT + ((long)b << 20) + (long)d * 1024 + tt;
            p[0]    = f2b(f.x);
            p[1024] = f2b(f.y);
            p[2048] = f2b(f.z);
            p[3072] = f2b(f.w);
          }
        }
      }
    }
  }
}

// ---------------------------------------------------------------------------
// Row softmax of mag (row, 1024) BF16 -> attn (row, 1024) bf16.
// ---------------------------------------------------------------------------
DEVI float wred_max(float v) {
#pragma unroll
  for (int o = 32; o > 0; o >>= 1) v = fmaxf(v, __shfl_xor(v, o));
  return v;
}
DEVI float wred_sum(float v) {
#pragma unroll
  for (int o = 32; o > 0; o >>= 1) v += __shfl_xor(v, o);
  return v;
}

__global__ __launch_bounds__(256) void softmax_kernel(
    const unsigned short* __restrict__ mag, unsigned short* __restrict__ attn) {
  const int row = blockIdx.x;
  const int tid = threadIdx.x;
  const int wave = tid >> 6, lane = tid & 63;
  ushort4 u4 = *reinterpret_cast<const ushort4*>(mag + (long)row * 1024 + tid * 4);
  float m4x = b2f(u4.x), m4y = b2f(u4.y), m4z = b2f(u4.z), m4w = b2f(u4.w);
  float mx = fmaxf(fmaxf(m4x, m4y), fmaxf(m4z, m4w));
  mx = wred_max(mx);
  __shared__ float sred[8];
  if (lane == 0) sred[wave] = mx;
  __syncthreads();
  mx = fmaxf(fmaxf(sred[0], sred[1]), fmaxf(sred[2], sred[3]));
  float e[4];
  e[0] = expf(m4x - mx); e[1] = expf(m4y - mx);
  e[2] = expf(m4z - mx); e[3] = expf(m4w - mx);
  float s = e[0] + e[1] + e[2] + e[3];
  s = wred_sum(s);
  if (lane == 0) sred[4 + wave] = s;
  __syncthreads();
  s = sred[4] + sred[5] + sred[6] + sred[7];
  const float inv = 1.0f / s;
  ushort4 o;
  o.x = f2b(e[0] * inv); o.y = f2b(e[1] * inv);
  o.z = f2b(e[2] * inv); o.w = f2b(e[3] * inv);
  *reinterpret_cast<ushort4*>(attn + (long)row * 1024 + tid * 4) = o;
}

// ---------------------------------------------------------------------------
extern "C" void kernel_launch(void* const* d_in, const int* in_sizes, int n_in,
                              void* d_out, int out_size, void* d_ws, size_t ws_size,
                              hipStream_t stream) {
  const float* xr = (const float*)d_in[0];
  const float* xi = (const float*)d_in[1];
  WArgs wa;
  for (int L = 0; L < 5; ++L) {
    wa.wr[L] = (const float*)d_in[2 + 4 * L + 0];
    wa.wi[L] = (const float*)d_in[2 + 4 * L + 1];
    wa.br[L] = (const float*)d_in[2 + 4 * L + 2];
    wa.bi[L] = (const float*)d_in[2 + 4 * L + 3];
  }

  char* ws = (char*)d_ws;
  size_t off = 0;
  auto alloc = [&](size_t bytes) {
    char* p = ws + off;
    off += (bytes + 255) & ~(size_t)255;
    return p;
  };
  unsigned short* W    = (unsigned short*)alloc(5l * 1024 * 1024 * 2);
  float*          bias = (float*)         alloc(5l * 1024 * 4);
  unsigned short* xp   = (unsigned short*)alloc(8192l * 1024 * 2);  // reused as attn
  unsigned short* y    = (unsigned short*)alloc(8192l * 1024 * 2);
  unsigned short* q    = (unsigned short*)alloc(8192l * 1024 * 2);  // reused as weighted
  unsigned short* kmod = (unsigned short*)alloc(8l * 2048 * 1024 * 2);
  unsigned short* vt   = (unsigned short*)alloc(8l * 1024 * 1024 * 2);
  unsigned short* mag  = (unsigned short*)alloc(8l * 1024 * 1024 * 2);
  (void)ws_size; (void)in_sizes; (void)n_in; (void)out_size;

  pack_x_kernel<<<8192, 256, 0, stream>>>(xr, xi, xp);
  pack_w_kernel<<<dim3(1024, 1, 5), 256, 0, stream>>>(wa, W, bias);

  // l1 (+bias, complex leaky relu): (8192x1024) @ W0^T  [2D grid]
  gemm3_kernel<0, true, true, 0><<<dim3(64, 4, 1), 512, 0, stream>>>(
      (const bf16*)xp, (const bf16*)W, y, nullptr, nullptr, bias,
      1024, 1024, 0, 0, 0);

  // fused q,k,v (+bias): (8192x1024) @ [W1;W2;W3]^T, N=3072  [2D grid]
  // (v written directly transposed into vt)
  gemm3_kernel<4, true, false, 0><<<dim3(64, 12, 1), 512, 0, stream>>>(
      (const bf16*)y, (const bf16*)(W + 1l * 1024 * 1024), q, kmod, vt,
      bias + 1024, 3072, 1024, 0, 0, 0);

  // scores -> |.|/sqrt(512) as bf16: per batch (1024x2048) = q_b @ kmod_b^T
  // [batch-to-XCD 1D grid, 512 blocks]
  gemm3_kernel<3, false, false, 2><<<dim3(512, 1, 1), 512, 0, stream>>>(
      (const bf16*)q, (const bf16*)kmod, mag, nullptr, nullptr, nullptr,
      2048, 1024, 1024l * 1024, 2048l * 1024, 1024l * 1024);

  softmax_kernel<<<8192, 256, 0, stream>>>(mag, xp /* attn */);

  // weighted: per batch (1024 x 1024) = attn_b @ vt_b^T
  // [batch-to-XCD 1D grid, 256 blocks]
  gemm3_kernel<0, false, false, 2><<<dim3(256, 1, 1), 512, 0, stream>>>(
      (const bf16*)xp, (const bf16*)vt, q /* weighted */, nullptr, nullptr,
      nullptr, 1024, 1024, 1024l * 1024, 1024l * 1024, 1024l * 1024);

  // l2 (+bias), split real/imag fp32 straight into d_out  [2D grid]
  gemm3_kernel<2, true, false, 0><<<dim3(64, 4, 1), 512, 0, stream>>>(
      (const bf16*)q, (const bf16*)(W + 4l * 1024 * 1024), d_out, nullptr,
      nullptr, bias + 4096, 1024, 1024, 0, 0, 0);
}

// Round 12
// 202.231 us; speedup vs baseline: 1.0614x; 1.0614x over previous
//
#include <hip/hip_runtime.h>
#include <hip/hip_bf16.h>
#include <stdint.h>

typedef __hip_bfloat16 bf16;
typedef __attribute__((ext_vector_type(8))) short short8;
typedef __attribute__((ext_vector_type(4))) float f32x4;

#define DEVI __device__ __forceinline__

static constexpr long IMAG_OFF = 8192l * 512;   // offset of imag plane in d_out

DEVI unsigned short f2b(float f) {
  bf16 h = __float2bfloat16(f);
  unsigned short u;
  __builtin_memcpy(&u, &h, 2);
  return u;
}

DEVI float b2f(unsigned short u) {
  unsigned int x = (unsigned int)u << 16;
  float f;
  __builtin_memcpy(&f, &x, 4);
  return f;
}

#define GLD16(g, l) __builtin_amdgcn_global_load_lds( \
    (const __attribute__((address_space(1))) void*)(g), \
    (__attribute__((address_space(3))) void*)(l), 16, 0, 0)

// ---------------------------------------------------------------------------
// Pack x_real/x_imag (fp32) -> xpack bf16 (8192, 1024) = [real | imag]
// ---------------------------------------------------------------------------
__global__ __launch_bounds__(256) void pack_x_kernel(
    const float* __restrict__ xr, const float* __restrict__ xi,
    unsigned short* __restrict__ xp) {
  const int t = blockIdx.x * 256 + threadIdx.x;
  const int m = t >> 8;
  const int d = (t & 255) * 4;
  const float* src = (d < 512) ? (xr + (long)m * 512 + d)
                               : (xi + (long)m * 512 + (d - 512));
  float4 v = *reinterpret_cast<const float4*>(src);
  ushort4 o;
  o.x = f2b(v.x); o.y = f2b(v.y); o.z = f2b(v.z); o.w = f2b(v.w);
  *reinterpret_cast<ushort4*>(xp + (long)m * 1024 + d) = o;
}

// ---------------------------------------------------------------------------
// Build Wbig (1024x1024 bf16) per layer: [[Wr, -Wi], [Wi, Wr]] and packed bias
// ---------------------------------------------------------------------------
struct WArgs {
  const float* wr[5]; const float* wi[5];
  const float* br[5]; const float* bi[5];
};

__global__ __launch_bounds__(256) void pack_w_kernel(
    WArgs a, unsigned short* __restrict__ W, float* __restrict__ bias) {
  const int L = blockIdx.z;
  const int t = blockIdx.x * 256 + threadIdx.x;
  const int n = t >> 8;
  const int k = (t & 255) * 4;
  const float* wr = a.wr[L]; const float* wi = a.wi[L];
  const float* src; float sgn = 1.0f;
  if (n < 512) {
    if (k < 512) src = wr + (long)n * 512 + k;
    else { src = wi + (long)n * 512 + (k - 512); sgn = -1.0f; }
  } else {
    if (k < 512) src = wi + (long)(n - 512) * 512 + k;
    else         src = wr + (long)(n - 512) * 512 + (k - 512);
  }
  float4 v = *reinterpret_cast<const float4*>(src);
  ushort4 o;
  o.x = f2b(sgn * v.x); o.y = f2b(sgn * v.y);
  o.z = f2b(sgn * v.z); o.w = f2b(sgn * v.w);
  *reinterpret_cast<ushort4*>(W + (long)L * 1024 * 1024 + (long)n * 1024 + k) = o;
  if (t < 1024)
    bias[L * 1024 + t] = (t < 512) ? a.br[L][t] : a.bi[L][t - 512];
}

// ---------------------------------------------------------------------------
// Shared epilogue for both GEMM kernels.
// OM: 0 = bf16 C (ldc=N); 2 = fp32 split re/im into d_out;
//     3 = |complex|/sqrt(512) interleaved re/im cols -> BF16 (ldc=1024);
//     4 = fused QKV epilogue (q plain, k -> interleaved kmod, v -> vt direct)
// ---------------------------------------------------------------------------
template<int OM, bool BIAS, bool ACT>
DEVI void epilogue_store(float4 f, long rm, int cn, int z, int N, long sC,
                         void* C0, void* C1, void* C2, const float* bias) {
  if (BIAS) {
    float4 b4 = *reinterpret_cast<const float4*>(bias + cn);
    f.x += b4.x; f.y += b4.y; f.z += b4.z; f.w += b4.w;
  }
  if (ACT) {
    f.x = (f.x >= 0.f) ? f.x : 0.01f * f.x;
    f.y = (f.y >= 0.f) ? f.y : 0.01f * f.y;
    f.z = (f.z >= 0.f) ? f.z : 0.01f * f.z;
    f.w = (f.w >= 0.f) ? f.w : 0.01f * f.w;
  }
  if (OM == 0) {
    unsigned short* C = (unsigned short*)C0 + (long)z * sC;
    ushort4 o; o.x = f2b(f.x); o.y = f2b(f.y); o.z = f2b(f.z); o.w = f2b(f.w);
    *reinterpret_cast<ushort4*>(C + rm * N + cn) = o;
  } else if (OM == 2) {
    float* O = (float*)C0;
    if (cn < 512) *reinterpret_cast<float4*>(O + rm * 512 + cn) = f;
    else          *reinterpret_cast<float4*>(O + IMAG_OFF + rm * 512 + (cn - 512)) = f;
  } else if (OM == 3) {
    // |s|/sqrt(512) stored as BF16 (halves mag traffic; softmax reads bf16)
    unsigned short* S = (unsigned short*)C0 + (long)z * sC;
    const float scale = 0.044194173824159216f;   // 1/sqrt(512)
    ushort2 o;
    o.x = f2b(sqrtf(f.x * f.x + f.y * f.y) * scale);
    o.y = f2b(sqrtf(f.z * f.z + f.w * f.w) * scale);
    *reinterpret_cast<ushort2*>(S + rm * 1024 + (cn >> 1)) = o;
  } else if (OM == 4) {
    if (cn < 1024) {            // q
      unsigned short* Q = (unsigned short*)C0;
      ushort4 o; o.x = f2b(f.x); o.y = f2b(f.y); o.z = f2b(f.z); o.w = f2b(f.w);
      *reinterpret_cast<ushort4*>(Q + rm * 1024 + cn) = o;
    } else if (cn < 2048) {     // k -> interleaved kmod
      const int d = cn - 1024;
      const int b = (int)(rm >> 10), tt = (int)(rm & 1023);
      unsigned short* KM = (unsigned short*)C1;
      const float s = (d < 512) ? 1.0f : -1.0f;
      ushort4 o1, o2;
      o1.x = f2b(s * f.x); o1.y = f2b(s * f.y);
      o1.z = f2b(s * f.z); o1.w = f2b(s * f.w);
      o2.x = f2b(f.x); o2.y = f2b(f.y); o2.z = f2b(f.z); o2.w = f2b(f.w);
      // row 2t: Re-transform [kr | -ki]; row 2t+1: Im-transform [ki | kr]
      *reinterpret_cast<ushort4*>(KM + ((long)(b << 11) + 2 * tt)     * 1024 + d)         = o1;
      *reinterpret_cast<ushort4*>(KM + ((long)(b << 11) + 2 * tt + 1) * 1024 + (d ^ 512)) = o2;
    } else {                    // v -> vt[b][d][t] directly (fused transpose)
      unsigned short* VT = (unsigned short*)C2;
      const int d = cn - 2048;
      const int b = (int)(rm >> 10), tt = (int)(rm & 1023);
      unsigned short* p = VT + ((long)b << 20) + (long)d * 1024 + tt;
      p[0]    = f2b(f.x);
      p[1024] = f2b(f.y);
      p[2048] = f2b(f.z);
      p[3072] = f2b(f.w);
    }
  }
}

// ---------------------------------------------------------------------------
// gemm_wide (r8/r10 PROVEN): 128(M) x 256(N) tile, BK=32, 512 thr = 8 waves
// (2M x 4N), wave 64x64, 16x16x32 MFMA. THREE LDS buffers (72 KiB -> 2
// blocks/CU), distance-2 prefetch ring, counted vmcnt(3), ONE barrier per
// K-tile, chunk-XOR swizzle (PMC: 0 conflicts), setprio. Fragment ds_reads
// AFTER the barrier (vmcnt is per-wave). Used for QKV (grid 768) and scores
// (GM=2 grid 512) -- grids >= 512 blocks.
// [r11 lesson: 32x32x16 shape regresses -- 16B store segments amplify
//  WRITE_SIZE 1.5x and matrix pipe wasn't the critical path.]
// GM: 0 = plain 2D/3D grid; 2 = batched 1D (z = id&7 pins batch -> XCD,
//     local = id>>3: bm = local&7, bn = local>>3).
// ---------------------------------------------------------------------------
template<int OM, bool BIAS, bool ACT, int GM>
__global__ __launch_bounds__(512) void gemm_wide_kernel(
    const bf16* __restrict__ A, const bf16* __restrict__ Bm,
    void* __restrict__ C0, void* __restrict__ C1, void* __restrict__ C2,
    const float* __restrict__ bias, int N, int K,
    long sA, long sB, long sC) {
  __shared__ __align__(16) bf16 sm[3 * 12288];   // buf: A 128x32 (8KB) + B 256x32 (16KB)
  const int tid  = threadIdx.x;
  const int lane = tid & 63, wave = tid >> 6;
  const int r = lane & 15, g = lane >> 4;
  const int wr = wave >> 2, wc = wave & 3;

  int bm, bn, z;
  if (GM == 2) {
    const int id = blockIdx.x;
    z = id & 7;                 // batch -> XCD (dispatch is round-robin id%8)
    const int local = id >> 3;
    bm = local & 7;
    bn = local >> 3;
  } else {
    bm = blockIdx.x; bn = blockIdx.y; z = blockIdx.z;
  }
  const int m0 = bm * 128, n0 = bn * 256;

  const bf16* Ab = A  + (long)z * sA;
  const bf16* Bb = Bm + (long)z * sB;
  const int srow = tid >> 2;
  const int schk = ((tid & 3) ^ ((tid >> 3) & 3)) * 8;
  const bf16* gA  = Ab + (long)(m0 + srow) * K + schk;
  const bf16* gB0 = Bb + (long)(n0 + srow) * K + schk;
  const bf16* gB1 = gB0 + (long)128 * K;
  char* const lb = (char*)sm + tid * 16;

#define STGW(buf, kt) do { \
    GLD16(gA  + (kt), lb + (buf) * 24576); \
    GLD16(gB0 + (kt), lb + (buf) * 24576 + 8192); \
    GLD16(gB1 + (kt), lb + (buf) * 24576 + 16384); } while (0)

  f32x4 acc[4][4] = {};
  const int sel = (g ^ ((r >> 1) & 3)) * 8;
  const int axoff = (wr * 64 + r) * 32 + sel;
  const int bxoff = 4096 + (wc * 64 + r) * 32 + sel;

  STGW(0, 0);
  STGW(1, 32);
  asm volatile("s_waitcnt vmcnt(3)" ::: "memory");
  __builtin_amdgcn_s_barrier();

  const int nt = K >> 5;
  int bc = 0, bs = 2;
  for (int t = 0; t < nt; ++t) {
    if (t + 2 < nt) STGW(bs, (t + 2) << 5);   // burst-issue distance-2 prefetch
    const bf16* S = sm + bc * 12288;
    short8 af[4], bq[4];
#pragma unroll
    for (int mi = 0; mi < 4; ++mi)
      af[mi] = *reinterpret_cast<const short8*>(S + axoff + mi * 512);
#pragma unroll
    for (int nj = 0; nj < 4; ++nj)
      bq[nj] = *reinterpret_cast<const short8*>(S + bxoff + nj * 512);
    __builtin_amdgcn_s_setprio(1);
#pragma unroll
    for (int mi = 0; mi < 4; ++mi)
#pragma unroll
      for (int nj = 0; nj < 4; ++nj)
        acc[mi][nj] = __builtin_amdgcn_mfma_f32_16x16x32_bf16(bq[nj], af[mi], acc[mi][nj], 0, 0, 0);
    __builtin_amdgcn_s_setprio(0);
    if (t < nt - 2) asm volatile("s_waitcnt vmcnt(3)" ::: "memory");
    else            asm volatile("s_waitcnt vmcnt(0)" ::: "memory");
    __builtin_amdgcn_s_barrier();
    bc = (bc == 2) ? 0 : bc + 1;
    bs = (bs == 2) ? 0 : bs + 1;
  }
#undef STGW

  const int rowbase = m0 + wr * 64 + r;
  const int colbase = n0 + wc * 64 + g * 4;
#pragma unroll
  for (int mi = 0; mi < 4; ++mi) {
    const long rm = rowbase + mi * 16;
#pragma unroll
    for (int nj = 0; nj < 4; ++nj) {
      const int cn = colbase + nj * 16;
      float4 f;
      f.x = acc[mi][nj][0]; f.y = acc[mi][nj][1];
      f.z = acc[mi][nj][2]; f.w = acc[mi][nj][3];
      epilogue_store<OM, BIAS, ACT>(f, rm, cn, z, N, sC, C0, C1, C2, bias);
    }
  }
}

// ---------------------------------------------------------------------------
// gemm_narrow (r9 PROVEN-correct): 128x128 tile, BK=32, 256 thr = 4 waves
// (2M x 2N), wave 64x64. THREE LDS buffers (48 KiB), distance-2 ring,
// counted vmcnt(4), one barrier/K-tile, same swizzle, setprio. Used ONLY for
// the small-grid GEMMs (l1, l2, weighted) whose 128x256 grids would be 256
// blocks = 1 block/CU; at 512 blocks this restores 2 blocks/CU overlap.
// ---------------------------------------------------------------------------
template<int OM, bool BIAS, bool ACT, int GM>
__global__ __launch_bounds__(256) void gemm_narrow_kernel(
    const bf16* __restrict__ A, const bf16* __restrict__ Bm,
    void* __restrict__ C0, void* __restrict__ C1, void* __restrict__ C2,
    const float* __restrict__ bias, int N, int K,
    long sA, long sB, long sC) {
  __shared__ __align__(16) bf16 sm[3 * 8192];   // buf: A 128x32 (8KB) + B 128x32 (8KB)
  const int tid  = threadIdx.x;
  const int lane = tid & 63, wave = tid >> 6;
  const int r = lane & 15, g = lane >> 4;
  const int wr = wave >> 1, wc = wave & 1;

  int bm, bn, z;
  if (GM == 2) {
    const int id = blockIdx.x;
    z = id & 7;                 // batch -> XCD
    const int local = id >> 3;
    bm = local & 7;             // M = 1024 -> 8 m-blocks
    bn = local >> 3;
  } else {
    bm = blockIdx.x; bn = blockIdx.y; z = blockIdx.z;
  }
  const int m0 = bm * 128, n0 = bn * 128;

  const bf16* Ab = A  + (long)z * sA;
  const bf16* Bb = Bm + (long)z * sB;
  const int srow = tid >> 2;
  const int schk = ((tid & 3) ^ ((tid >> 3) & 3)) * 8;
  const bf16* gA = Ab + (long)(m0 + srow) * K + schk;
  const bf16* gB = Bb + (long)(n0 + srow) * K + schk;
  const long K64 = (long)64 * K;
  char* const lb = (char*)sm + tid * 16;

#define STGN(buf, kt) do { \
    GLD16(gA + (kt),       lb + (buf) * 16384); \
    GLD16(gA + (kt) + K64, lb + (buf) * 16384 + 4096); \
    GLD16(gB + (kt),       lb + (buf) * 16384 + 8192); \
    GLD16(gB + (kt) + K64, lb + (buf) * 16384 + 12288); } while (0)

  f32x4 acc[4][4] = {};
  const int sel = (g ^ ((r >> 1) & 3)) * 8;
  const int axoff = (wr * 64 + r) * 32 + sel;
  const int bxoff = 4096 + (wc * 64 + r) * 32 + sel;

  STGN(0, 0);
  STGN(1, 32);
  asm volatile("s_waitcnt vmcnt(4)" ::: "memory");
  __builtin_amdgcn_s_barrier();

  const int nt = K >> 5;
  int bc = 0, bs = 2;
  for (int t = 0; t < nt; ++t) {
    if (t + 2 < nt) STGN(bs, (t + 2) << 5);
    const bf16* S = sm + bc * 8192;
    short8 af[4], bq[4];
#pragma unroll
    for (int mi = 0; mi < 4; ++mi)
      af[mi] = *reinterpret_cast<const short8*>(S + axoff + mi * 512);
#pragma unroll
    for (int nj = 0; nj < 4; ++nj)
      bq[nj] = *reinterpret_cast<const short8*>(S + bxoff + nj * 512);
    __builtin_amdgcn_s_setprio(1);
#pragma unroll
    for (int mi = 0; mi < 4; ++mi)
#pragma unroll
      for (int nj = 0; nj < 4; ++nj)
        acc[mi][nj] = __builtin_amdgcn_mfma_f32_16x16x32_bf16(bq[nj], af[mi], acc[mi][nj], 0, 0, 0);
    __builtin_amdgcn_s_setprio(0);
    if (t < nt - 2) asm volatile("s_waitcnt vmcnt(4)" ::: "memory");
    else            asm volatile("s_waitcnt vmcnt(0)" ::: "memory");
    __builtin_amdgcn_s_barrier();
    bc = (bc == 2) ? 0 : bc + 1;
    bs = (bs == 2) ? 0 : bs + 1;
  }
#undef STGN

  const int rowbase = m0 + wr * 64 + r;
  const int colbase = n0 + wc * 64 + g * 4;
#pragma unroll
  for (int mi = 0; mi < 4; ++mi) {
    const long rm = rowbase + mi * 16;
#pragma unroll
    for (int nj = 0; nj < 4; ++nj) {
      const int cn = colbase + nj * 16;
      float4 f;
      f.x = acc[mi][nj][0]; f.y = acc[mi][nj][1];
      f.z = acc[mi][nj][2]; f.w = acc[mi][nj][3];
      epilogue_store<OM, BIAS, ACT>(f, rm, cn, z, N, sC, C0, C1, C2, bias);
    }
  }
}

// ---------------------------------------------------------------------------
// Row softmax of mag (row, 1024) BF16 -> attn (row, 1024) bf16.
// ---------------------------------------------------------------------------
DEVI float wred_max(float v) {
#pragma unroll
  for (int o = 32; o > 0; o >>= 1) v = fmaxf(v, __shfl_xor(v, o));
  return v;
}
DEVI float wred_sum(float v) {
#pragma unroll
  for (int o = 32; o > 0; o >>= 1) v += __shfl_xor(v, o);
  return v;
}

__global__ __launch_bounds__(256) void softmax_kernel(
    const unsigned short* __restrict__ mag, unsigned short* __restrict__ attn) {
  const int row = blockIdx.x;
  const int tid = threadIdx.x;
  const int wave = tid >> 6, lane = tid & 63;
  ushort4 u4 = *reinterpret_cast<const ushort4*>(mag + (long)row * 1024 + tid * 4);
  float m4x = b2f(u4.x), m4y = b2f(u4.y), m4z = b2f(u4.z), m4w = b2f(u4.w);
  float mx = fmaxf(fmaxf(m4x, m4y), fmaxf(m4z, m4w));
  mx = wred_max(mx);
  __shared__ float sred[8];
  if (lane == 0) sred[wave] = mx;
  __syncthreads();
  mx = fmaxf(fmaxf(sred[0], sred[1]), fmaxf(sred[2], sred[3]));
  float e[4];
  e[0] = expf(m4x - mx); e[1] = expf(m4y - mx);
  e[2] = expf(m4z - mx); e[3] = expf(m4w - mx);
  float s = e[0] + e[1] + e[2] + e[3];
  s = wred_sum(s);
  if (lane == 0) sred[4 + wave] = s;
  __syncthreads();
  s = sred[4] + sred[5] + sred[6] + sred[7];
  const float inv = 1.0f / s;
  ushort4 o;
  o.x = f2b(e[0] * inv); o.y = f2b(e[1] * inv);
  o.z = f2b(e[2] * inv); o.w = f2b(e[3] * inv);
  *reinterpret_cast<ushort4*>(attn + (long)row * 1024 + tid * 4) = o;
}

// ---------------------------------------------------------------------------
extern "C" void kernel_launch(void* const* d_in, const int* in_sizes, int n_in,
                              void* d_out, int out_size, void* d_ws, size_t ws_size,
                              hipStream_t stream) {
  const float* xr = (const float*)d_in[0];
  const float* xi = (const float*)d_in[1];
  WArgs wa;
  for (int L = 0; L < 5; ++L) {
    wa.wr[L] = (const float*)d_in[2 + 4 * L + 0];
    wa.wi[L] = (const float*)d_in[2 + 4 * L + 1];
    wa.br[L] = (const float*)d_in[2 + 4 * L + 2];
    wa.bi[L] = (const float*)d_in[2 + 4 * L + 3];
  }

  char* ws = (char*)d_ws;
  size_t off = 0;
  auto alloc = [&](size_t bytes) {
    char* p = ws + off;
    off += (bytes + 255) & ~(size_t)255;
    return p;
  };
  unsigned short* W    = (unsigned short*)alloc(5l * 1024 * 1024 * 2);
  float*          bias = (float*)         alloc(5l * 1024 * 4);
  unsigned short* xp   = (unsigned short*)alloc(8192l * 1024 * 2);  // reused as attn
  unsigned short* y    = (unsigned short*)alloc(8192l * 1024 * 2);
  unsigned short* q    = (unsigned short*)alloc(8192l * 1024 * 2);  // reused as weighted
  unsigned short* kmod = (unsigned short*)alloc(8l * 2048 * 1024 * 2);
  unsigned short* vt   = (unsigned short*)alloc(8l * 1024 * 1024 * 2);
  unsigned short* mag  = (unsigned short*)alloc(8l * 1024 * 1024 * 2);
  (void)ws_size; (void)in_sizes; (void)n_in; (void)out_size;

  pack_x_kernel<<<8192, 256, 0, stream>>>(xr, xi, xp);
  pack_w_kernel<<<dim3(1024, 1, 5), 256, 0, stream>>>(wa, W, bias);

  // l1 (+bias, complex leaky relu): (8192x1024) @ W0^T
  // [narrow 128x128, 512 blocks -> 2 blocks/CU]
  gemm_narrow_kernel<0, true, true, 0><<<dim3(64, 8, 1), 256, 0, stream>>>(
      (const bf16*)xp, (const bf16*)W, y, nullptr, nullptr, bias,
      1024, 1024, 0, 0, 0);

  // fused q,k,v (+bias): (8192x1024) @ [W1;W2;W3]^T, N=3072
  // [wide 128x256, 2D grid 768 blocks; v written directly transposed into vt]
  gemm_wide_kernel<4, true, false, 0><<<dim3(64, 12, 1), 512, 0, stream>>>(
      (const bf16*)y, (const bf16*)(W + 1l * 1024 * 1024), q, kmod, vt,
      bias + 1024, 3072, 1024, 0, 0, 0);

  // scores -> |.|/sqrt(512) as bf16: per batch (1024x2048) = q_b @ kmod_b^T
  // [wide, batch-to-XCD 1D grid, 512 blocks]
  gemm_wide_kernel<3, false, false, 2><<<dim3(512, 1, 1), 512, 0, stream>>>(
      (const bf16*)q, (const bf16*)kmod, mag, nullptr, nullptr, nullptr,
      2048, 1024, 1024l * 1024, 2048l * 1024, 1024l * 1024);

  softmax_kernel<<<8192, 256, 0, stream>>>(mag, xp /* attn */);

  // weighted: per batch (1024 x 1024) = attn_b @ vt_b^T
  // [narrow, batch-to-XCD 1D grid, 512 blocks -> 2 blocks/CU]
  gemm_narrow_kernel<0, false, false, 2><<<dim3(512, 1, 1), 256, 0, stream>>>(
      (const bf16*)xp, (const bf16*)vt, q /* weighted */, nullptr, nullptr,
      nullptr, 1024, 1024, 1024l * 1024, 1024l * 1024, 1024l * 1024);

  // l2 (+bias), split real/imag fp32 straight into d_out
  // [narrow 128x128, 512 blocks]
  gemm_narrow_kernel<2, true, false, 0><<<dim3(64, 8, 1), 256, 0, stream>>>(
      (const bf16*)q, (const bf16*)(W + 4l * 1024 * 1024), d_out, nullptr,
      nullptr, bias + 4096, 1024, 1024, 0, 0, 0);
}

// Round 13
// 199.300 us; speedup vs baseline: 1.0771x; 1.0147x over previous
//
#include <hip/hip_runtime.h>
#include <hip/hip_bf16.h>
#include <stdint.h>

typedef __hip_bfloat16 bf16;
typedef __attribute__((ext_vector_type(8))) short short8;
typedef __attribute__((ext_vector_type(4))) float f32x4;

#define DEVI __device__ __forceinline__

static constexpr long IMAG_OFF = 8192l * 512;   // offset of imag plane in d_out

DEVI unsigned short f2b(float f) {
  bf16 h = __float2bfloat16(f);
  unsigned short u;
  __builtin_memcpy(&u, &h, 2);
  return u;
}

DEVI float b2f(unsigned short u) {
  unsigned int x = (unsigned int)u << 16;
  float f;
  __builtin_memcpy(&f, &x, 4);
  return f;
}

#define GLD16(g, l) __builtin_amdgcn_global_load_lds( \
    (const __attribute__((address_space(1))) void*)(g), \
    (__attribute__((address_space(3))) void*)(l), 16, 0, 0)

// ---------------------------------------------------------------------------
// Pack x_real/x_imag (fp32) -> xpack bf16 (8192, 1024) = [real | imag]
// ---------------------------------------------------------------------------
__global__ __launch_bounds__(256) void pack_x_kernel(
    const float* __restrict__ xr, const float* __restrict__ xi,
    unsigned short* __restrict__ xp) {
  const int t = blockIdx.x * 256 + threadIdx.x;
  const int m = t >> 8;
  const int d = (t & 255) * 4;
  const float* src = (d < 512) ? (xr + (long)m * 512 + d)
                               : (xi + (long)m * 512 + (d - 512));
  float4 v = *reinterpret_cast<const float4*>(src);
  ushort4 o;
  o.x = f2b(v.x); o.y = f2b(v.y); o.z = f2b(v.z); o.w = f2b(v.w);
  *reinterpret_cast<ushort4*>(xp + (long)m * 1024 + d) = o;
}

// ---------------------------------------------------------------------------
// Build Wbig (1024x1024 bf16) per layer: [[Wr, -Wi], [Wi, Wr]] and packed bias
// ---------------------------------------------------------------------------
struct WArgs {
  const float* wr[5]; const float* wi[5];
  const float* br[5]; const float* bi[5];
};

__global__ __launch_bounds__(256) void pack_w_kernel(
    WArgs a, unsigned short* __restrict__ W, float* __restrict__ bias) {
  const int L = blockIdx.z;
  const int t = blockIdx.x * 256 + threadIdx.x;
  const int n = t >> 8;
  const int k = (t & 255) * 4;
  const float* wr = a.wr[L]; const float* wi = a.wi[L];
  const float* src; float sgn = 1.0f;
  if (n < 512) {
    if (k < 512) src = wr + (long)n * 512 + k;
    else { src = wi + (long)n * 512 + (k - 512); sgn = -1.0f; }
  } else {
    if (k < 512) src = wi + (long)(n - 512) * 512 + k;
    else         src = wr + (long)(n - 512) * 512 + (k - 512);
  }
  float4 v = *reinterpret_cast<const float4*>(src);
  ushort4 o;
  o.x = f2b(sgn * v.x); o.y = f2b(sgn * v.y);
  o.z = f2b(sgn * v.z); o.w = f2b(sgn * v.w);
  *reinterpret_cast<ushort4*>(W + (long)L * 1024 * 1024 + (long)n * 1024 + k) = o;
  if (t < 1024)
    bias[L * 1024 + t] = (t < 512) ? a.br[L][t] : a.bi[L][t - 512];
}

// ---------------------------------------------------------------------------
// gemm3 (r8/r10 PROVEN config -- session optimum): C[m,n] = sum_k A[m,k]*B[n,k]
// Tile 128(M) x 256(N), BK=32, 512 threads = 8 waves (2M x 4N), wave 64x64,
// 16x16x32 MFMA. THREE LDS buffers (72 KiB -> 2 blocks/CU), distance-2
// prefetch ring, counted vmcnt(3), ONE barrier per K-tile, chunk-XOR swizzle
// (PMC: 0 conflicts), setprio. Fragment ds_reads AFTER the barrier (vmcnt is
// per-wave; cross-wave LDS visibility needs the barrier).
// Session lessons baked in: [r9/r12] 128x128 tiles regress (thinner barrier
// intervals); [r11] 32x32x16 MFMA regresses (16B store segments -> 1.5x
// WRITE_SIZE; matrix pipe not critical path); [r3/r5] deep-phase 256^2
// schedules regress at K=1024 (fill/drain overhead, 1 block/CU);
// [r7] bm-major XCD chunking thrashes L2 on non-batched GEMMs.
// GM: 0 = plain 2D/3D grid (best for non-batched GEMMs, r7/r8 measured)
//     2 = batched 1D: z = id&7 pins batch -> XCD (working set ~fits L2);
//         local = id>>3: bm = local&7, bn = local>>3.
// OM: 0 = bf16 C (ldc=N)
//     2 = fp32 split real/imag into d_out
//     3 = |complex|/sqrt(512) from interleaved re/im cols -> BF16 (ldc=1024)
//     4 = fused QKV epilogue (q plain, k -> interleaved kmod, v -> vt direct)
// ---------------------------------------------------------------------------
template<int OM, bool BIAS, bool ACT, int GM>
__global__ __launch_bounds__(512) void gemm3_kernel(
    const bf16* __restrict__ A, const bf16* __restrict__ Bm,
    void* __restrict__ C0, void* __restrict__ C1, void* __restrict__ C2,
    const float* __restrict__ bias, int N, int K,
    long sA, long sB, long sC) {
  __shared__ __align__(16) bf16 sm[3 * 12288];   // buf: A 128x32 (8KB) + B 256x32 (16KB)
  const int tid  = threadIdx.x;
  const int lane = tid & 63, wave = tid >> 6;
  const int r = lane & 15, g = lane >> 4;
  const int wr = wave >> 2, wc = wave & 3;

  int bm, bn, z;
  if (GM == 2) {
    const int id = blockIdx.x;
    z = id & 7;                 // batch -> XCD (dispatch is round-robin id%8)
    const int local = id >> 3;
    bm = local & 7;
    bn = local >> 3;
  } else {
    bm = blockIdx.x; bn = blockIdx.y; z = blockIdx.z;
  }
  const int m0 = bm * 128, n0 = bn * 256;

  const bf16* Ab = A  + (long)z * sA;
  const bf16* Bb = Bm + (long)z * sB;
  // staging: linear LDS dest (gload_lds requirement); source chunk
  // pre-swizzled: (tid&3) ^ ((row>>1)&3), row = tid>>2
  const int srow = tid >> 2;
  const int schk = ((tid & 3) ^ ((tid >> 3) & 3)) * 8;
  const bf16* gA  = Ab + (long)(m0 + srow) * K + schk;
  const bf16* gB0 = Bb + (long)(n0 + srow) * K + schk;
  const bf16* gB1 = gB0 + (long)128 * K;
  char* const lb = (char*)sm + tid * 16;

#define STG3(buf, kt) do { \
    GLD16(gA  + (kt), lb + (buf) * 24576); \
    GLD16(gB0 + (kt), lb + (buf) * 24576 + 8192); \
    GLD16(gB1 + (kt), lb + (buf) * 24576 + 16384); } while (0)

  f32x4 acc[4][4] = {};
  // read swizzle matches staging: chunk g -> g ^ ((row>>1)&3)
  const int sel = (g ^ ((r >> 1) & 3)) * 8;
  const int axoff = (wr * 64 + r) * 32 + sel;
  const int bxoff = 4096 + (wc * 64 + r) * 32 + sel;

  STG3(0, 0);
  STG3(1, 32);
  asm volatile("s_waitcnt vmcnt(3)" ::: "memory");
  __builtin_amdgcn_s_barrier();

  const int nt = K >> 5;
  int bc = 0, bs = 2;
  for (int t = 0; t < nt; ++t) {
    if (t + 2 < nt) STG3(bs, (t + 2) << 5);   // burst-issue distance-2 prefetch
    const bf16* S = sm + bc * 12288;
    short8 af[4], bq[4];
#pragma unroll
    for (int mi = 0; mi < 4; ++mi)
      af[mi] = *reinterpret_cast<const short8*>(S + axoff + mi * 512);
#pragma unroll
    for (int nj = 0; nj < 4; ++nj)
      bq[nj] = *reinterpret_cast<const short8*>(S + bxoff + nj * 512);
    __builtin_amdgcn_s_setprio(1);
#pragma unroll
    for (int mi = 0; mi < 4; ++mi)
#pragma unroll
      for (int nj = 0; nj < 4; ++nj)
        acc[mi][nj] = __builtin_amdgcn_mfma_f32_16x16x32_bf16(bq[nj], af[mi], acc[mi][nj], 0, 0, 0);
    __builtin_amdgcn_s_setprio(0);
    // counted gate: tile t+1 guaranteed in LDS for ALL waves only after the
    // barrier below (vmcnt is per-wave).
    if (t < nt - 2) asm volatile("s_waitcnt vmcnt(3)" ::: "memory");
    else            asm volatile("s_waitcnt vmcnt(0)" ::: "memory");
    __builtin_amdgcn_s_barrier();
    bc = (bc == 2) ? 0 : bc + 1;
    bs = (bs == 2) ? 0 : bs + 1;
  }
#undef STG3

  // epilogue: D = mfma(B_frag, A_frag) -> row(m) = lane&15, col(n) = g*4+reg
  const int rowbase = m0 + wr * 64 + r;
  const int colbase = n0 + wc * 64 + g * 4;
#pragma unroll
  for (int mi = 0; mi < 4; ++mi) {
    const long rm = rowbase + mi * 16;
#pragma unroll
    for (int nj = 0; nj < 4; ++nj) {
      const int cn = colbase + nj * 16;
      float4 f;
      f.x = acc[mi][nj][0]; f.y = acc[mi][nj][1];
      f.z = acc[mi][nj][2]; f.w = acc[mi][nj][3];
      if (BIAS) {
        float4 b4 = *reinterpret_cast<const float4*>(bias + cn);
        f.x += b4.x; f.y += b4.y; f.z += b4.z; f.w += b4.w;
      }
      if (ACT) {
        f.x = (f.x >= 0.f) ? f.x : 0.01f * f.x;
        f.y = (f.y >= 0.f) ? f.y : 0.01f * f.y;
        f.z = (f.z >= 0.f) ? f.z : 0.01f * f.z;
        f.w = (f.w >= 0.f) ? f.w : 0.01f * f.w;
      }
      if (OM == 0) {
        unsigned short* C = (unsigned short*)C0 + (long)z * sC;
        ushort4 o; o.x = f2b(f.x); o.y = f2b(f.y); o.z = f2b(f.z); o.w = f2b(f.w);
        *reinterpret_cast<ushort4*>(C + rm * N + cn) = o;
      } else if (OM == 2) {
        float* O = (float*)C0;
        if (cn < 512) *reinterpret_cast<float4*>(O + rm * 512 + cn) = f;
        else          *reinterpret_cast<float4*>(O + IMAG_OFF + rm * 512 + (cn - 512)) = f;
      } else if (OM == 3) {
        // |s|/sqrt(512) stored as BF16 (halves mag traffic; softmax reads bf16)
        unsigned short* S = (unsigned short*)C0 + (long)z * sC;
        const float scale = 0.044194173824159216f;   // 1/sqrt(512)
        ushort2 o;
        o.x = f2b(sqrtf(f.x * f.x + f.y * f.y) * scale);
        o.y = f2b(sqrtf(f.z * f.z + f.w * f.w) * scale);
        *reinterpret_cast<ushort2*>(S + rm * 1024 + (cn >> 1)) = o;
      } else if (OM == 4) {
        if (cn < 1024) {            // q
          unsigned short* Q = (unsigned short*)C0;
          ushort4 o; o.x = f2b(f.x); o.y = f2b(f.y); o.z = f2b(f.z); o.w = f2b(f.w);
          *reinterpret_cast<ushort4*>(Q + rm * 1024 + cn) = o;
        } else if (cn < 2048) {     // k -> interleaved kmod
          const int d = cn - 1024;
          const int b = (int)(rm >> 10), tt = (int)(rm & 1023);
          unsigned short* KM = (unsigned short*)C1;
          const float s = (d < 512) ? 1.0f : -1.0f;
          ushort4 o1, o2;
          o1.x = f2b(s * f.x); o1.y = f2b(s * f.y);
          o1.z = f2b(s * f.z); o1.w = f2b(s * f.w);
          o2.x = f2b(f.x); o2.y = f2b(f.y); o2.z = f2b(f.z); o2.w = f2b(f.w);
          // row 2t: Re-transform [kr | -ki]; row 2t+1: Im-transform [ki | kr]
          *reinterpret_cast<ushort4*>(KM + ((long)(b << 11) + 2 * tt)     * 1024 + d)         = o1;
          *reinterpret_cast<ushort4*>(KM + ((long)(b << 11) + 2 * tt + 1) * 1024 + (d ^ 512)) = o2;
        } else {                    // v -> vt[b][d][t] directly (fused transpose)
          unsigned short* VT = (unsigned short*)C2;
          const int d = cn - 2048;
          const int b = (int)(rm >> 10), tt = (int)(rm & 1023);
          unsigned short* p = VT + ((long)b << 20) + (long)d * 1024 + tt;
          p[0]    = f2b(f.x);
          p[1024] = f2b(f.y);
          p[2048] = f2b(f.z);
          p[3072] = f2b(f.w);
        }
      }
    }
  }
}

// ---------------------------------------------------------------------------
// Row softmax of mag (row, 1024) BF16 -> attn (row, 1024) bf16.
// ---------------------------------------------------------------------------
DEVI float wred_max(float v) {
#pragma unroll
  for (int o = 32; o > 0; o >>= 1) v = fmaxf(v, __shfl_xor(v, o));
  return v;
}
DEVI float wred_sum(float v) {
#pragma unroll
  for (int o = 32; o > 0; o >>= 1) v += __shfl_xor(v, o);
  return v;
}

__global__ __launch_bounds__(256) void softmax_kernel(
    const unsigned short* __restrict__ mag, unsigned short* __restrict__ attn) {
  const int row = blockIdx.x;
  const int tid = threadIdx.x;
  const int wave = tid >> 6, lane = tid & 63;
  ushort4 u4 = *reinterpret_cast<const ushort4*>(mag + (long)row * 1024 + tid * 4);
  float m4x = b2f(u4.x), m4y = b2f(u4.y), m4z = b2f(u4.z), m4w = b2f(u4.w);
  float mx = fmaxf(fmaxf(m4x, m4y), fmaxf(m4z, m4w));
  mx = wred_max(mx);
  __shared__ float sred[8];
  if (lane == 0) sred[wave] = mx;
  __syncthreads();
  mx = fmaxf(fmaxf(sred[0], sred[1]), fmaxf(sred[2], sred[3]));
  float e[4];
  e[0] = expf(m4x - mx); e[1] = expf(m4y - mx);
  e[2] = expf(m4z - mx); e[3] = expf(m4w - mx);
  float s = e[0] + e[1] + e[2] + e[3];
  s = wred_sum(s);
  if (lane == 0) sred[4 + wave] = s;
  __syncthreads();
  s = sred[4] + sred[5] + sred[6] + sred[7];
  const float inv = 1.0f / s;
  ushort4 o;
  o.x = f2b(e[0] * inv); o.y = f2b(e[1] * inv);
  o.z = f2b(e[2] * inv); o.w = f2b(e[3] * inv);
  *reinterpret_cast<ushort4*>(attn + (long)row * 1024 + tid * 4) = o;
}

// ---------------------------------------------------------------------------
extern "C" void kernel_launch(void* const* d_in, const int* in_sizes, int n_in,
                              void* d_out, int out_size, void* d_ws, size_t ws_size,
                              hipStream_t stream) {
  const float* xr = (const float*)d_in[0];
  const float* xi = (const float*)d_in[1];
  WArgs wa;
  for (int L = 0; L < 5; ++L) {
    wa.wr[L] = (const float*)d_in[2 + 4 * L + 0];
    wa.wi[L] = (const float*)d_in[2 + 4 * L + 1];
    wa.br[L] = (const float*)d_in[2 + 4 * L + 2];
    wa.bi[L] = (const float*)d_in[2 + 4 * L + 3];
  }

  char* ws = (char*)d_ws;
  size_t off = 0;
  auto alloc = [&](size_t bytes) {
    char* p = ws + off;
    off += (bytes + 255) & ~(size_t)255;
    return p;
  };
  unsigned short* W    = (unsigned short*)alloc(5l * 1024 * 1024 * 2);
  float*          bias = (float*)         alloc(5l * 1024 * 4);
  unsigned short* xp   = (unsigned short*)alloc(8192l * 1024 * 2);  // reused as attn
  unsigned short* y    = (unsigned short*)alloc(8192l * 1024 * 2);
  unsigned short* q    = (unsigned short*)alloc(8192l * 1024 * 2);  // reused as weighted
  unsigned short* kmod = (unsigned short*)alloc(8l * 2048 * 1024 * 2);
  unsigned short* vt   = (unsigned short*)alloc(8l * 1024 * 1024 * 2);
  unsigned short* mag  = (unsigned short*)alloc(8l * 1024 * 1024 * 2);
  (void)ws_size; (void)in_sizes; (void)n_in; (void)out_size;

  pack_x_kernel<<<8192, 256, 0, stream>>>(xr, xi, xp);
  pack_w_kernel<<<dim3(1024, 1, 5), 256, 0, stream>>>(wa, W, bias);

  // l1 (+bias, complex leaky relu): (8192x1024) @ W0^T  [2D grid]
  gemm3_kernel<0, true, true, 0><<<dim3(64, 4, 1), 512, 0, stream>>>(
      (const bf16*)xp, (const bf16*)W, y, nullptr, nullptr, bias,
      1024, 1024, 0, 0, 0);

  // fused q,k,v (+bias): (8192x1024) @ [W1;W2;W3]^T, N=3072  [2D grid]
  // (v written directly transposed into vt)
  gemm3_kernel<4, true, false, 0><<<dim3(64, 12, 1), 512, 0, stream>>>(
      (const bf16*)y, (const bf16*)(W + 1l * 1024 * 1024), q, kmod, vt,
      bias + 1024, 3072, 1024, 0, 0, 0);

  // scores -> |.|/sqrt(512) as bf16: per batch (1024x2048) = q_b @ kmod_b^T
  // [batch-to-XCD 1D grid, 512 blocks]
  gemm3_kernel<3, false, false, 2><<<dim3(512, 1, 1), 512, 0, stream>>>(
      (const bf16*)q, (const bf16*)kmod, mag, nullptr, nullptr, nullptr,
      2048, 1024, 1024l * 1024, 2048l * 1024, 1024l * 1024);

  softmax_kernel<<<8192, 256, 0, stream>>>(mag, xp /* attn */);

  // weighted: per batch (1024 x 1024) = attn_b @ vt_b^T
  // [batch-to-XCD 1D grid, 256 blocks]
  gemm3_kernel<0, false, false, 2><<<dim3(256, 1, 1), 512, 0, stream>>>(
      (const bf16*)xp, (const bf16*)vt, q /* weighted */, nullptr, nullptr,
      nullptr, 1024, 1024, 1024l * 1024, 1024l * 1024, 1024l * 1024);

  // l2 (+bias), split real/imag fp32 straight into d_out  [2D grid]
  gemm3_kernel<2, true, false, 0><<<dim3(64, 4, 1), 512, 0, stream>>>(
      (const bf16*)q, (const bf16*)(W + 4l * 1024 * 1024), d_out, nullptr,
      nullptr, bias + 4096, 1024, 1024, 0, 0, 0);
}

// Round 14
// 197.587 us; speedup vs baseline: 1.0864x; 1.0087x over previous
//
#include <hip/hip_runtime.h>
#include <hip/hip_bf16.h>
#include <stdint.h>

typedef __hip_bfloat16 bf16;
typedef __attribute__((ext_vector_type(8))) short short8;
typedef __attribute__((ext_vector_type(4))) float f32x4;

#define DEVI __device__ __forceinline__

static constexpr long IMAG_OFF = 8192l * 512;   // offset of imag plane in d_out

DEVI unsigned short f2b(float f) {
  bf16 h = __float2bfloat16(f);
  unsigned short u;
  __builtin_memcpy(&u, &h, 2);
  return u;
}

DEVI float b2f(unsigned short u) {
  unsigned int x = (unsigned int)u << 16;
  float f;
  __builtin_memcpy(&f, &x, 4);
  return f;
}

#define GLD16(g, l) __builtin_amdgcn_global_load_lds( \
    (const __attribute__((address_space(1))) void*)(g), \
    (__attribute__((address_space(3))) void*)(l), 16, 0, 0)

// ---------------------------------------------------------------------------
// Merged pack kernel (r14): one dispatch does BOTH
//   blocks [0, 8192):      x_real/x_imag (fp32) -> xpack bf16 (8192,1024)
//   blocks [8192, 13312):  per-layer Wbig (1024x1024 bf16) = [[Wr,-Wi],[Wi,Wr]]
//                          + packed bias (1024 fp32 per layer)
// The two phases are independent; merging removes one launch + one grid-drain
// tail vs. the serial pair (same stream = serialized dispatches).
// ---------------------------------------------------------------------------
struct WArgs {
  const float* wr[5]; const float* wi[5];
  const float* br[5]; const float* bi[5];
};

__global__ __launch_bounds__(256) void pack_all_kernel(
    const float* __restrict__ xr, const float* __restrict__ xi,
    unsigned short* __restrict__ xp,
    WArgs a, unsigned short* __restrict__ W, float* __restrict__ bias) {
  const int bid = blockIdx.x;
  if (bid < 8192) {
    // ---- pack_x ----
    const int t = bid * 256 + threadIdx.x;
    const int m = t >> 8;
    const int d = (t & 255) * 4;
    const float* src = (d < 512) ? (xr + (long)m * 512 + d)
                                 : (xi + (long)m * 512 + (d - 512));
    float4 v = *reinterpret_cast<const float4*>(src);
    ushort4 o;
    o.x = f2b(v.x); o.y = f2b(v.y); o.z = f2b(v.z); o.w = f2b(v.w);
    *reinterpret_cast<ushort4*>(xp + (long)m * 1024 + d) = o;
  } else {
    // ---- pack_w ----
    const int pid = bid - 8192;           // 0 .. 5119
    const int L = pid >> 10;              // layer 0..4
    const int t = (pid & 1023) * 256 + threadIdx.x;
    const int n = t >> 8;
    const int k = (t & 255) * 4;
    const float* wr = a.wr[L]; const float* wi = a.wi[L];
    const float* src; float sgn = 1.0f;
    if (n < 512) {
      if (k < 512) src = wr + (long)n * 512 + k;
      else { src = wi + (long)n * 512 + (k - 512); sgn = -1.0f; }
    } else {
      if (k < 512) src = wi + (long)(n - 512) * 512 + k;
      else         src = wr + (long)(n - 512) * 512 + (k - 512);
    }
    float4 v = *reinterpret_cast<const float4*>(src);
    ushort4 o;
    o.x = f2b(sgn * v.x); o.y = f2b(sgn * v.y);
    o.z = f2b(sgn * v.z); o.w = f2b(sgn * v.w);
    *reinterpret_cast<ushort4*>(W + (long)L * 1024 * 1024 + (long)n * 1024 + k) = o;
    if (t < 1024)
      bias[L * 1024 + t] = (t < 512) ? a.br[L][t] : a.bi[L][t - 512];
  }
}

// ---------------------------------------------------------------------------
// gemm3 (r8/r10 PROVEN config -- session optimum): C[m,n] = sum_k A[m,k]*B[n,k]
// Tile 128(M) x 256(N), BK=32, 512 threads = 8 waves (2M x 4N), wave 64x64,
// 16x16x32 MFMA. THREE LDS buffers (72 KiB -> 2 blocks/CU), distance-2
// prefetch ring, counted vmcnt(3), ONE barrier per K-tile, chunk-XOR swizzle
// (PMC: 0 conflicts), setprio. Fragment ds_reads AFTER the barrier (vmcnt is
// per-wave; cross-wave LDS visibility needs the barrier).
// Session lessons baked in: [r9/r12] 128x128 tiles regress (thinner barrier
// intervals); [r11] 32x32x16 MFMA regresses (16B store segments -> 1.5x
// WRITE_SIZE; matrix pipe not critical path); [r3/r5] deep-phase 256^2
// schedules regress at K=1024 (fill/drain overhead, 1 block/CU);
// [r7] bm-major XCD chunking thrashes L2 on non-batched GEMMs.
// GM: 0 = plain 2D/3D grid (best for non-batched GEMMs, r7/r8 measured)
//     2 = batched 1D: z = id&7 pins batch -> XCD (working set ~fits L2);
//         local = id>>3: bm = local&7, bn = local>>3.
// OM: 0 = bf16 C (ldc=N)
//     2 = fp32 split real/imag into d_out
//     3 = |complex|/sqrt(512) from interleaved re/im cols -> BF16 (ldc=1024)
//     4 = fused QKV epilogue (q plain, k -> interleaved kmod, v -> vt direct)
// ---------------------------------------------------------------------------
template<int OM, bool BIAS, bool ACT, int GM>
__global__ __launch_bounds__(512) void gemm3_kernel(
    const bf16* __restrict__ A, const bf16* __restrict__ Bm,
    void* __restrict__ C0, void* __restrict__ C1, void* __restrict__ C2,
    const float* __restrict__ bias, int N, int K,
    long sA, long sB, long sC) {
  __shared__ __align__(16) bf16 sm[3 * 12288];   // buf: A 128x32 (8KB) + B 256x32 (16KB)
  const int tid  = threadIdx.x;
  const int lane = tid & 63, wave = tid >> 6;
  const int r = lane & 15, g = lane >> 4;
  const int wr = wave >> 2, wc = wave & 3;

  int bm, bn, z;
  if (GM == 2) {
    const int id = blockIdx.x;
    z = id & 7;                 // batch -> XCD (dispatch is round-robin id%8)
    const int local = id >> 3;
    bm = local & 7;
    bn = local >> 3;
  } else {
    bm = blockIdx.x; bn = blockIdx.y; z = blockIdx.z;
  }
  const int m0 = bm * 128, n0 = bn * 256;

  const bf16* Ab = A  + (long)z * sA;
  const bf16* Bb = Bm + (long)z * sB;
  // staging: linear LDS dest (gload_lds requirement); source chunk
  // pre-swizzled: (tid&3) ^ ((row>>1)&3), row = tid>>2
  const int srow = tid >> 2;
  const int schk = ((tid & 3) ^ ((tid >> 3) & 3)) * 8;
  const bf16* gA  = Ab + (long)(m0 + srow) * K + schk;
  const bf16* gB0 = Bb + (long)(n0 + srow) * K + schk;
  const bf16* gB1 = gB0 + (long)128 * K;
  char* const lb = (char*)sm + tid * 16;

#define STG3(buf, kt) do { \
    GLD16(gA  + (kt), lb + (buf) * 24576); \
    GLD16(gB0 + (kt), lb + (buf) * 24576 + 8192); \
    GLD16(gB1 + (kt), lb + (buf) * 24576 + 16384); } while (0)

  f32x4 acc[4][4] = {};
  // read swizzle matches staging: chunk g -> g ^ ((row>>1)&3)
  const int sel = (g ^ ((r >> 1) & 3)) * 8;
  const int axoff = (wr * 64 + r) * 32 + sel;
  const int bxoff = 4096 + (wc * 64 + r) * 32 + sel;

  STG3(0, 0);
  STG3(1, 32);
  asm volatile("s_waitcnt vmcnt(3)" ::: "memory");
  __builtin_amdgcn_s_barrier();

  const int nt = K >> 5;
  int bc = 0, bs = 2;
  for (int t = 0; t < nt; ++t) {
    if (t + 2 < nt) STG3(bs, (t + 2) << 5);   // burst-issue distance-2 prefetch
    const bf16* S = sm + bc * 12288;
    short8 af[4], bq[4];
#pragma unroll
    for (int mi = 0; mi < 4; ++mi)
      af[mi] = *reinterpret_cast<const short8*>(S + axoff + mi * 512);
#pragma unroll
    for (int nj = 0; nj < 4; ++nj)
      bq[nj] = *reinterpret_cast<const short8*>(S + bxoff + nj * 512);
    __builtin_amdgcn_s_setprio(1);
#pragma unroll
    for (int mi = 0; mi < 4; ++mi)
#pragma unroll
      for (int nj = 0; nj < 4; ++nj)
        acc[mi][nj] = __builtin_amdgcn_mfma_f32_16x16x32_bf16(bq[nj], af[mi], acc[mi][nj], 0, 0, 0);
    __builtin_amdgcn_s_setprio(0);
    // counted gate: tile t+1 guaranteed in LDS for ALL waves only after the
    // barrier below (vmcnt is per-wave).
    if (t < nt - 2) asm volatile("s_waitcnt vmcnt(3)" ::: "memory");
    else            asm volatile("s_waitcnt vmcnt(0)" ::: "memory");
    __builtin_amdgcn_s_barrier();
    bc = (bc == 2) ? 0 : bc + 1;
    bs = (bs == 2) ? 0 : bs + 1;
  }
#undef STG3

  // epilogue: D = mfma(B_frag, A_frag) -> row(m) = lane&15, col(n) = g*4+reg
  const int rowbase = m0 + wr * 64 + r;
  const int colbase = n0 + wc * 64 + g * 4;
#pragma unroll
  for (int mi = 0; mi < 4; ++mi) {
    const long rm = rowbase + mi * 16;
#pragma unroll
    for (int nj = 0; nj < 4; ++nj) {
      const int cn = colbase + nj * 16;
      float4 f;
      f.x = acc[mi][nj][0]; f.y = acc[mi][nj][1];
      f.z = acc[mi][nj][2]; f.w = acc[mi][nj][3];
      if (BIAS) {
        float4 b4 = *reinterpret_cast<const float4*>(bias + cn);
        f.x += b4.x; f.y += b4.y; f.z += b4.z; f.w += b4.w;
      }
      if (ACT) {
        f.x = (f.x >= 0.f) ? f.x : 0.01f * f.x;
        f.y = (f.y >= 0.f) ? f.y : 0.01f * f.y;
        f.z = (f.z >= 0.f) ? f.z : 0.01f * f.z;
        f.w = (f.w >= 0.f) ? f.w : 0.01f * f.w;
      }
      if (OM == 0) {
        unsigned short* C = (unsigned short*)C0 + (long)z * sC;
        ushort4 o; o.x = f2b(f.x); o.y = f2b(f.y); o.z = f2b(f.z); o.w = f2b(f.w);
        *reinterpret_cast<ushort4*>(C + rm * N + cn) = o;
      } else if (OM == 2) {
        float* O = (float*)C0;
        if (cn < 512) *reinterpret_cast<float4*>(O + rm * 512 + cn) = f;
        else          *reinterpret_cast<float4*>(O + IMAG_OFF + rm * 512 + (cn - 512)) = f;
      } else if (OM == 3) {
        // |s|/sqrt(512) stored as BF16 (halves mag traffic; softmax reads bf16)
        unsigned short* S = (unsigned short*)C0 + (long)z * sC;
        const float scale = 0.044194173824159216f;   // 1/sqrt(512)
        ushort2 o;
        o.x = f2b(sqrtf(f.x * f.x + f.y * f.y) * scale);
        o.y = f2b(sqrtf(f.z * f.z + f.w * f.w) * scale);
        *reinterpret_cast<ushort2*>(S + rm * 1024 + (cn >> 1)) = o;
      } else if (OM == 4) {
        if (cn < 1024) {            // q
          unsigned short* Q = (unsigned short*)C0;
          ushort4 o; o.x = f2b(f.x); o.y = f2b(f.y); o.z = f2b(f.z); o.w = f2b(f.w);
          *reinterpret_cast<ushort4*>(Q + rm * 1024 + cn) = o;
        } else if (cn < 2048) {     // k -> interleaved kmod
          const int d = cn - 1024;
          const int b = (int)(rm >> 10), tt = (int)(rm & 1023);
          unsigned short* KM = (unsigned short*)C1;
          const float s = (d < 512) ? 1.0f : -1.0f;
          ushort4 o1, o2;
          o1.x = f2b(s * f.x); o1.y = f2b(s * f.y);
          o1.z = f2b(s * f.z); o1.w = f2b(s * f.w);
          o2.x = f2b(f.x); o2.y = f2b(f.y); o2.z = f2b(f.z); o2.w = f2b(f.w);
          // row 2t: Re-transform [kr | -ki]; row 2t+1: Im-transform [ki | kr]
          *reinterpret_cast<ushort4*>(KM + ((long)(b << 11) + 2 * tt)     * 1024 + d)         = o1;
          *reinterpret_cast<ushort4*>(KM + ((long)(b << 11) + 2 * tt + 1) * 1024 + (d ^ 512)) = o2;
        } else {                    // v -> vt[b][d][t] directly (fused transpose)
          unsigned short* VT = (unsigned short*)C2;
          const int d = cn - 2048;
          const int b = (int)(rm >> 10), tt = (int)(rm & 1023);
          unsigned short* p = VT + ((long)b << 20) + (long)d * 1024 + tt;
          p[0]    = f2b(f.x);
          p[1024] = f2b(f.y);
          p[2048] = f2b(f.z);
          p[3072] = f2b(f.w);
        }
      }
    }
  }
}

// ---------------------------------------------------------------------------
// Row softmax of mag (row, 1024) BF16 -> attn (row, 1024) bf16.
// ---------------------------------------------------------------------------
DEVI float wred_max(float v) {
#pragma unroll
  for (int o = 32; o > 0; o >>= 1) v = fmaxf(v, __shfl_xor(v, o));
  return v;
}
DEVI float wred_sum(float v) {
#pragma unroll
  for (int o = 32; o > 0; o >>= 1) v += __shfl_xor(v, o);
  return v;
}

__global__ __launch_bounds__(256) void softmax_kernel(
    const unsigned short* __restrict__ mag, unsigned short* __restrict__ attn) {
  const int row = blockIdx.x;
  const int tid = threadIdx.x;
  const int wave = tid >> 6, lane = tid & 63;
  ushort4 u4 = *reinterpret_cast<const ushort4*>(mag + (long)row * 1024 + tid * 4);
  float m4x = b2f(u4.x), m4y = b2f(u4.y), m4z = b2f(u4.z), m4w = b2f(u4.w);
  float mx = fmaxf(fmaxf(m4x, m4y), fmaxf(m4z, m4w));
  mx = wred_max(mx);
  __shared__ float sred[8];
  if (lane == 0) sred[wave] = mx;
  __syncthreads();
  mx = fmaxf(fmaxf(sred[0], sred[1]), fmaxf(sred[2], sred[3]));
  float e[4];
  e[0] = expf(m4x - mx); e[1] = expf(m4y - mx);
  e[2] = expf(m4z - mx); e[3] = expf(m4w - mx);
  float s = e[0] + e[1] + e[2] + e[3];
  s = wred_sum(s);
  if (lane == 0) sred[4 + wave] = s;
  __syncthreads();
  s = sred[4] + sred[5] + sred[6] + sred[7];
  const float inv = 1.0f / s;
  ushort4 o;
  o.x = f2b(e[0] * inv); o.y = f2b(e[1] * inv);
  o.z = f2b(e[2] * inv); o.w = f2b(e[3] * inv);
  *reinterpret_cast<ushort4*>(attn + (long)row * 1024 + tid * 4) = o;
}

// ---------------------------------------------------------------------------
extern "C" void kernel_launch(void* const* d_in, const int* in_sizes, int n_in,
                              void* d_out, int out_size, void* d_ws, size_t ws_size,
                              hipStream_t stream) {
  const float* xr = (const float*)d_in[0];
  const float* xi = (const float*)d_in[1];
  WArgs wa;
  for (int L = 0; L < 5; ++L) {
    wa.wr[L] = (const float*)d_in[2 + 4 * L + 0];
    wa.wi[L] = (const float*)d_in[2 + 4 * L + 1];
    wa.br[L] = (const float*)d_in[2 + 4 * L + 2];
    wa.bi[L] = (const float*)d_in[2 + 4 * L + 3];
  }

  char* ws = (char*)d_ws;
  size_t off = 0;
  auto alloc = [&](size_t bytes) {
    char* p = ws + off;
    off += (bytes + 255) & ~(size_t)255;
    return p;
  };
  unsigned short* W    = (unsigned short*)alloc(5l * 1024 * 1024 * 2);
  float*          bias = (float*)         alloc(5l * 1024 * 4);
  unsigned short* xp   = (unsigned short*)alloc(8192l * 1024 * 2);  // reused as attn
  unsigned short* y    = (unsigned short*)alloc(8192l * 1024 * 2);
  unsigned short* q    = (unsigned short*)alloc(8192l * 1024 * 2);  // reused as weighted
  unsigned short* kmod = (unsigned short*)alloc(8l * 2048 * 1024 * 2);
  unsigned short* vt   = (unsigned short*)alloc(8l * 1024 * 1024 * 2);
  unsigned short* mag  = (unsigned short*)alloc(8l * 1024 * 1024 * 2);
  (void)ws_size; (void)in_sizes; (void)n_in; (void)out_size;

  // merged pack: x -> xpack AND W/bias pack in one dispatch (saves one
  // launch + one grid-drain tail; phases independent)
  pack_all_kernel<<<13312, 256, 0, stream>>>(xr, xi, xp, wa, W, bias);

  // l1 (+bias, complex leaky relu): (8192x1024) @ W0^T  [2D grid]
  gemm3_kernel<0, true, true, 0><<<dim3(64, 4, 1), 512, 0, stream>>>(
      (const bf16*)xp, (const bf16*)W, y, nullptr, nullptr, bias,
      1024, 1024, 0, 0, 0);

  // fused q,k,v (+bias): (8192x1024) @ [W1;W2;W3]^T, N=3072  [2D grid]
  // (v written directly transposed into vt)
  gemm3_kernel<4, true, false, 0><<<dim3(64, 12, 1), 512, 0, stream>>>(
      (const bf16*)y, (const bf16*)(W + 1l * 1024 * 1024), q, kmod, vt,
      bias + 1024, 3072, 1024, 0, 0, 0);

  // scores -> |.|/sqrt(512) as bf16: per batch (1024x2048) = q_b @ kmod_b^T
  // [batch-to-XCD 1D grid, 512 blocks]
  gemm3_kernel<3, false, false, 2><<<dim3(512, 1, 1), 512, 0, stream>>>(
      (const bf16*)q, (const bf16*)kmod, mag, nullptr, nullptr, nullptr,
      2048, 1024, 1024l * 1024, 2048l * 1024, 1024l * 1024);

  softmax_kernel<<<8192, 256, 0, stream>>>(mag, xp /* attn */);

  // weighted: per batch (1024 x 1024) = attn_b @ vt_b^T
  // [batch-to-XCD 1D grid, 256 blocks]
  gemm3_kernel<0, false, false, 2><<<dim3(256, 1, 1), 512, 0, stream>>>(
      (const bf16*)xp, (const bf16*)vt, q /* weighted */, nullptr, nullptr,
      nullptr, 1024, 1024, 1024l * 1024, 1024l * 1024, 1024l * 1024);

  // l2 (+bias), split real/imag fp32 straight into d_out  [2D grid]
  gemm3_kernel<2, true, false, 0><<<dim3(64, 4, 1), 512, 0, stream>>>(
      (const bf16*)q, (const bf16*)(W + 4l * 1024 * 1024), d_out, nullptr,
      nullptr, bias + 4096, 1024, 1024, 0, 0, 0);
}